// Round 9
// baseline (539.718 us; speedup 1.0000x reference)
//
#include <hip/hip_runtime.h>

#define N_NODES 100000
#define N_EDGES 1600000
#define NBKT 391            // bucket = dst >> 8, 256 nodes per bucket
#define EPB 4096            // edges per block in bucket passes
#define NBLK_E ((N_EDGES + EPB - 1) / EPB)  // 391

typedef unsigned short u16;
typedef unsigned int u32;
typedef u32 u32x4 __attribute__((ext_vector_type(4)));  // clang vector: ok for nontemporal builtins
struct alignas(8) bf4 { u16 a, b, c, d; };

__device__ __forceinline__ float blo(u32 u) { return __uint_as_float(u << 16); }
__device__ __forceinline__ float bhi(u32 u) { return __uint_as_float(u & 0xffff0000u); }
__device__ __forceinline__ u16 f2bf(float f) {  // RTNE
  u32 u = __float_as_uint(f);
  return (u16)((u + 0x7fffu + ((u >> 16) & 1u)) >> 16);
}
__device__ __forceinline__ u32 pack2(float a, float b) {
  return (u32)f2bf(a) | ((u32)f2bf(b) << 16);
}

// ---------------- CSR build: two-level bucket counting sort ----------------

__global__ __launch_bounds__(256) void bucket_count_k(const int* __restrict__ dst,
                                                      int* __restrict__ gCount) {
  __shared__ int h[NBKT];
  for (int i = threadIdx.x; i < NBKT; i += 256) h[i] = 0;
  __syncthreads();
  const int e0 = blockIdx.x * EPB;
  const int eN = min(EPB, N_EDGES - e0);
  for (int i = threadIdx.x; i < eN; i += 256) atomicAdd(&h[dst[e0 + i] >> 8], 1);
  __syncthreads();
  for (int i = threadIdx.x; i < NBKT; i += 256)
    if (h[i]) atomicAdd(&gCount[i], h[i]);
}

__global__ void bucket_scan_k(const int* __restrict__ gCount,
                              int* __restrict__ gBase,
                              int* __restrict__ gCursor,
                              int* __restrict__ offsets) {
  __shared__ int sm[512];
  const int t = threadIdx.x;  // 256
  const int c0 = (t < NBKT) ? gCount[t] : 0;
  const int c1 = (t + 256 < NBKT) ? gCount[t + 256] : 0;
  sm[t] = c0; sm[t + 256] = c1;
  __syncthreads();
  for (int off = 1; off < 512; off <<= 1) {
    const int v0 = (t >= off) ? sm[t - off] : 0;
    const int v1 = (t + 256 >= off) ? sm[t + 256 - off] : 0;
    __syncthreads();
    sm[t] += v0; sm[t + 256] += v1;
    __syncthreads();
  }
  if (t < NBKT)       { const int b = sm[t] - c0;       gBase[t] = b;       gCursor[t] = b; }
  if (t + 256 < NBKT) { const int b = sm[t + 256] - c1; gBase[t + 256] = b; gCursor[t + 256] = b; }
  if (t == 0) { gBase[NBKT] = N_EDGES; offsets[N_NODES] = N_EDGES; }
}

// chunk -> LDS counting-sort by bucket -> coalesced run writes into ebuf
__global__ __launch_bounds__(256) void bucket_scatter_k(const int* __restrict__ src,
                                                        const int* __restrict__ dst,
                                                        int* __restrict__ gCursor,
                                                        uint2* __restrict__ ebuf) {
  __shared__ int cnt[NBKT];
  __shared__ int inc[512];
  __shared__ int gb[NBKT];
  __shared__ int cur[NBKT];
  __shared__ uint2 st[EPB];
  const int t = threadIdx.x;
  for (int i = t; i < NBKT; i += 256) cnt[i] = 0;
  __syncthreads();
  const int e0 = blockIdx.x * EPB;
  const int eN = min(EPB, N_EDGES - e0);
  for (int i = t; i < eN; i += 256) atomicAdd(&cnt[dst[e0 + i] >> 8], 1);
  __syncthreads();
  const int c0 = (t < NBKT) ? cnt[t] : 0;
  const int c1 = (t + 256 < NBKT) ? cnt[t + 256] : 0;
  inc[t] = c0; inc[t + 256] = c1;
  __syncthreads();
  for (int off = 1; off < 512; off <<= 1) {
    const int v0 = (t >= off) ? inc[t - off] : 0;
    const int v1 = (t + 256 >= off) ? inc[t + 256 - off] : 0;
    __syncthreads();
    inc[t] += v0; inc[t + 256] += v1;
    __syncthreads();
  }
  if (t < NBKT) {
    if (c0) gb[t] = atomicAdd(&gCursor[t], c0);
    cur[t] = inc[t] - c0;
  }
  if (t + 256 < NBKT) {
    if (c1) gb[t + 256] = atomicAdd(&gCursor[t + 256], c1);
    cur[t + 256] = inc[t + 256] - c1;
  }
  __syncthreads();
  for (int i = t; i < eN; i += 256) {
    const int d = dst[e0 + i];
    const int b = d >> 8;
    const int p = atomicAdd(&cur[b], 1);
    st[p] = make_uint2((unsigned)src[e0 + i], (unsigned)d);
  }
  __syncthreads();
  for (int i = t; i < eN; i += 256) {
    const uint2 e = st[i];
    const int b = (int)(e.y >> 8);
    const int excl = inc[b] - cnt[b];
    ebuf[gb[b] + (i - excl)] = e;   // adjacent i in a run -> adjacent addrs
  }
}

// one block per bucket: per-node count/scan/scatter in LDS; emits offsets,
// dis/selfn, and csr_src (src in low 20 bits).
__global__ __launch_bounds__(256) void csr_build_k(const uint2* __restrict__ ebuf,
                                                   const int* __restrict__ gBase,
                                                   int* __restrict__ offsets,
                                                   int* __restrict__ csr_src,
                                                   float* __restrict__ dis,
                                                   float* __restrict__ selfn) {
  __shared__ int cnt[256];
  __shared__ int inc[256];
  __shared__ int cur[256];
  const int t = threadIdx.x;
  const int b = blockIdx.x;
  const int ebeg = gBase[b], eend = gBase[b + 1];
  cnt[t] = 0;
  __syncthreads();
  for (int e = ebeg + t; e < eend; e += 256) atomicAdd(&cnt[ebuf[e].y & 255], 1);
  __syncthreads();
  const int c = cnt[t];
  inc[t] = c;
  __syncthreads();
  for (int off = 1; off < 256; off <<= 1) {
    const int v = (t >= off) ? inc[t - off] : 0;
    __syncthreads();
    inc[t] += v;
    __syncthreads();
  }
  const int node = (b << 8) + t;
  const int goff = ebeg + inc[t] - c;
  cur[t] = goff;
  if (node < N_NODES) {
    offsets[node] = goff;
    const float deg = (float)c + 1.0f;  // +1 self loop
    dis[node] = rsqrtf(deg);
    selfn[node] = 1.0f / deg;
  }
  __syncthreads();
  for (int e = ebeg + t; e < eend; e += 256) {
    const uint2 ed = ebuf[e];
    const int p = atomicAdd(&cur[ed.y & 255], 1);
    csr_src[p] = (int)ed.x;
  }
}

// fold edge weight: csr2[i] = (src, dis[src]) — one random 4B gather per edge
// ONCE instead of per-layer.
__global__ __launch_bounds__(256) void pack_k(const int* __restrict__ csr_src,
                                              const float* __restrict__ dis,
                                              int2* __restrict__ csr2) {
  const int i = blockIdx.x * 256 + threadIdx.x;
  if (i < N_EDGES) {
    const int v = csr_src[i] & 0xFFFFF;
    csr2[i] = make_int2(v, __float_as_int(dis[v]));
  }
}

// ---------------- GEMM: out[N,C] = act(A)[N,K] @ W[K,C] + bias, bf16 out ------
// BF16IN: A is bf16 (u16*), staged via 8B vector loads; else fp32 via float4.
// act = identity (BN=false) or relu(a*scale[k]+shift[k]) (BN=true).

template <int K, int C, int RPT, bool BN, bool BF16IN>
__global__ __launch_bounds__(256) void gemm_k(const void* __restrict__ Av,
                                              const float* __restrict__ W,
                                              const float* __restrict__ bias,
                                              const float* __restrict__ scale,
                                              const float* __restrict__ shift,
                                              u16* __restrict__ out) {
  constexpr int CQ = C / 4;        // float4 channel groups
  constexpr int TR = 256 / CQ;     // thread row-slots (floor)
  constexpr int ROWS = TR * RPT;   // rows per block
  __shared__ __align__(16) float Wl[K * C];
  __shared__ __align__(16) float Al[ROWS * K];
  const int tid = threadIdx.x;
  for (int i = tid; i < K * C; i += 256) Wl[i] = W[i];
  const int row0 = blockIdx.x * ROWS;
  // staging: 4 elements per step, coalesced
  for (int i = tid; i < ROWS * K / 4; i += 256) {
    const int e0 = i * 4;
    const int r = e0 / K, k = e0 - (e0 / K) * K;
    const int gr = row0 + r;
    float v0 = 0.f, v1 = 0.f, v2 = 0.f, v3 = 0.f;
    if (gr < N_NODES) {
      if (BF16IN) {
        const uint2 u = *(const uint2*)((const u16*)Av + (size_t)gr * K + k);
        v0 = blo(u.x); v1 = bhi(u.x); v2 = blo(u.y); v3 = bhi(u.y);
      } else {
        const float4 a = *(const float4*)((const float*)Av + (size_t)gr * K + k);
        v0 = a.x; v1 = a.y; v2 = a.z; v3 = a.w;
      }
      if (BN) {
        const float4 sc = *(const float4*)(scale + k);
        const float4 sh = *(const float4*)(shift + k);
        v0 = fmaxf(fmaf(v0, sc.x, sh.x), 0.f);
        v1 = fmaxf(fmaf(v1, sc.y, sh.y), 0.f);
        v2 = fmaxf(fmaf(v2, sc.z, sh.z), 0.f);
        v3 = fmaxf(fmaf(v3, sc.w, sh.w), 0.f);
      }
    }
    *(float4*)(Al + r * K + k) = make_float4(v0, v1, v2, v3);
  }
  __syncthreads();
  const int cq = tid % CQ;
  const int rs = tid / CQ;
  if (rs >= TR) return;  // only when 256 % CQ != 0 (C=40); no further barriers
  const float4* W4 = (const float4*)Wl;
  const float4* A4 = (const float4*)Al;
  float4 acc[RPT];
#pragma unroll
  for (int i = 0; i < RPT; ++i) acc[i] = make_float4(0.f, 0.f, 0.f, 0.f);
#pragma unroll 4
  for (int k4 = 0; k4 < K / 4; ++k4) {
    float4 w0 = W4[(4 * k4 + 0) * CQ + cq];
    float4 w1 = W4[(4 * k4 + 1) * CQ + cq];
    float4 w2 = W4[(4 * k4 + 2) * CQ + cq];
    float4 w3 = W4[(4 * k4 + 3) * CQ + cq];
#pragma unroll
    for (int i = 0; i < RPT; ++i) {
      float4 a = A4[(rs * RPT + i) * (K / 4) + k4];
      acc[i].x = fmaf(a.x, w0.x, acc[i].x); acc[i].y = fmaf(a.x, w0.y, acc[i].y);
      acc[i].z = fmaf(a.x, w0.z, acc[i].z); acc[i].w = fmaf(a.x, w0.w, acc[i].w);
      acc[i].x = fmaf(a.y, w1.x, acc[i].x); acc[i].y = fmaf(a.y, w1.y, acc[i].y);
      acc[i].z = fmaf(a.y, w1.z, acc[i].z); acc[i].w = fmaf(a.y, w1.w, acc[i].w);
      acc[i].x = fmaf(a.z, w2.x, acc[i].x); acc[i].y = fmaf(a.z, w2.y, acc[i].y);
      acc[i].z = fmaf(a.z, w2.z, acc[i].z); acc[i].w = fmaf(a.z, w2.w, acc[i].w);
      acc[i].x = fmaf(a.w, w3.x, acc[i].x); acc[i].y = fmaf(a.w, w3.y, acc[i].y);
      acc[i].z = fmaf(a.w, w3.z, acc[i].z); acc[i].w = fmaf(a.w, w3.w, acc[i].w);
    }
  }
  float4 b4 = ((const float4*)bias)[cq];
#pragma unroll
  for (int i = 0; i < RPT; ++i) {
    int gr = row0 + rs * RPT + i;
    if (gr < N_NODES) {
      bf4 o;
      o.a = f2bf(acc[i].x + b4.x); o.b = f2bf(acc[i].y + b4.y);
      o.c = f2bf(acc[i].z + b4.z); o.d = f2bf(acc[i].w + b4.w);
      *(bf4*)(out + (size_t)gr * C + cq * 4) = o;
    }
  }
}

// ---------------- aggregation v4: v3 + nontemporal row gathers ---------------
// Wave = 8 groups x 8 lanes, 4 nodes per wave (2 groups per node). Random row
// gathers bypass L1 allocation (__builtin_nontemporal_load) — experiment
// against the per-CU L1 miss-handling wall. Output written as bf16 for the
// next layer's GEMM; BN stats computed in fp32.

template <bool STATS>
__global__ __launch_bounds__(256) void agg64_v4_k(const u16* __restrict__ tb,
                                                  const int2* __restrict__ csr2,
                                                  const int* __restrict__ offs,
                                                  const float* __restrict__ dis,
                                                  const float* __restrict__ selfn,
                                                  u16* __restrict__ out,
                                                  float* __restrict__ part) {
  __shared__ float s_sum[64];
  __shared__ float s_sq[64];
  if (STATS) {
    if (threadIdx.x < 64) { s_sum[threadIdx.x] = 0.f; s_sq[threadIdx.x] = 0.f; }
    __syncthreads();
  }
  const int lane = threadIdx.x & 63;
  const int nb = (blockIdx.x * 4 + (threadIdx.x >> 6)) * 4;
  const int g = lane >> 3;
  const int c4 = lane & 7;
  const int i = g >> 1;
  const int p = g & 1;
  const int node = nb + i;
  int beg = 0, end = 0;
  if (node < N_NODES) { beg = offs[node]; end = offs[node + 1]; }
  int iters = (end - beg + 1) >> 1;            // ceil(deg/2)
  iters = max(iters, __shfl_xor(iters, 8));    // wave-max across groups
  iters = max(iters, __shfl_xor(iters, 16));
  iters = max(iters, __shfl_xor(iters, 32));
  float acc[8];
#pragma unroll
  for (int k = 0; k < 8; ++k) acc[k] = 0.f;
  const u16* __restrict__ tc = tb + (c4 << 3);
  int e = beg + p;
#pragma unroll 4
  for (int it = 0; it < iters; ++it) {
    int2 ev = make_int2(0, 0);
    if (e < end) ev = csr2[e];
    e += 2;
    const int s = ev.x & 0xFFFFF;
    const float w = __int_as_float(ev.y);      // 0 when inactive
    const u32x4 q = __builtin_nontemporal_load((const u32x4*)(tc + (size_t)s * 64));
    acc[0] = fmaf(blo(q.x), w, acc[0]);
    acc[1] = fmaf(bhi(q.x), w, acc[1]);
    acc[2] = fmaf(blo(q.y), w, acc[2]);
    acc[3] = fmaf(bhi(q.y), w, acc[3]);
    acc[4] = fmaf(blo(q.z), w, acc[4]);
    acc[5] = fmaf(bhi(q.z), w, acc[5]);
    acc[6] = fmaf(blo(q.w), w, acc[6]);
    acc[7] = fmaf(bhi(q.w), w, acc[7]);
  }
  // combine the node's two groups (single butterfly step)
#pragma unroll
  for (int k = 0; k < 8; ++k) acc[k] += __shfl_xor(acc[k], 8);
  float v[8];
  const bool writer = (p == 0) && (node < N_NODES);
  if (writer) {
    const float dn = dis[node], sn = selfn[node];
    const uint4 q = *(const uint4*)(tb + (size_t)node * 64 + (c4 << 3));
    const float sv[8] = {blo(q.x), bhi(q.x), blo(q.y), bhi(q.y),
                         blo(q.z), bhi(q.z), blo(q.w), bhi(q.w)};
#pragma unroll
    for (int k = 0; k < 8; ++k) v[k] = fmaf(dn, acc[k], sv[k] * sn);
    uint4 o;
    o.x = pack2(v[0], v[1]); o.y = pack2(v[2], v[3]);
    o.z = pack2(v[4], v[5]); o.w = pack2(v[6], v[7]);
    *(uint4*)(out + (size_t)node * 64 + (c4 << 3)) = o;
  }
  if (STATS) {
    if (writer) {
#pragma unroll
      for (int k = 0; k < 8; ++k) {
        atomicAdd(&s_sum[(c4 << 3) + k], v[k]);
        atomicAdd(&s_sq[(c4 << 3) + k], v[k] * v[k]);
      }
    }
    __syncthreads();
    if (threadIdx.x < 128) {
      const int c = threadIdx.x & 63;
      const float val = (threadIdx.x < 64) ? s_sum[c] : s_sq[c];
      atomicAdd(&part[(blockIdx.x & 63) * 128 + (threadIdx.x < 64 ? c : 64 + c)], val);
    }
  }
}

// C=40 variant: 12 groups of 5 lanes (lanes 60..63 idle); 3 groups per node;
// lane loads 8 bf16 (row = 80 B = 5 x 16 B, aligned). fp32 out.
__global__ __launch_bounds__(256) void agg40_v4_k(const u16* __restrict__ tb,
                                                  const int2* __restrict__ csr2,
                                                  const int* __restrict__ offs,
                                                  const float* __restrict__ dis,
                                                  const float* __restrict__ selfn,
                                                  float* __restrict__ out) {
  const int lane = threadIdx.x & 63;
  const int nb = (blockIdx.x * 4 + (threadIdx.x >> 6)) * 4;
  const bool ok = lane < 60;
  const int g = ok ? (lane / 5) : 0;
  const int c4 = ok ? (lane - g * 5) : 0;
  const int i = g / 3;
  const int p = g - i * 3;
  const int node = nb + i;
  int beg = 0, end = 0;
  if (ok && node < N_NODES) { beg = offs[node]; end = offs[node + 1]; }
  int iters = (end - beg + 2) / 3;             // ceil(deg/3)
  iters = max(iters, __shfl_xor(iters, 1));
  iters = max(iters, __shfl_xor(iters, 2));
  iters = max(iters, __shfl_xor(iters, 4));
  iters = max(iters, __shfl_xor(iters, 8));
  iters = max(iters, __shfl_xor(iters, 16));
  iters = max(iters, __shfl_xor(iters, 32));
  float acc[8];
#pragma unroll
  for (int k = 0; k < 8; ++k) acc[k] = 0.f;
  const u16* __restrict__ tc = tb + (c4 << 3);
  int e = beg + p;
#pragma unroll 4
  for (int it = 0; it < iters; ++it) {
    int2 ev = make_int2(0, 0);
    if (e < end) ev = csr2[e];
    e += 3;
    const int s = ev.x & 0xFFFFF;
    const float w = __int_as_float(ev.y);
    const u32x4 q = __builtin_nontemporal_load((const u32x4*)(tc + (size_t)s * 40));
    acc[0] = fmaf(blo(q.x), w, acc[0]);
    acc[1] = fmaf(bhi(q.x), w, acc[1]);
    acc[2] = fmaf(blo(q.y), w, acc[2]);
    acc[3] = fmaf(bhi(q.y), w, acc[3]);
    acc[4] = fmaf(blo(q.z), w, acc[4]);
    acc[5] = fmaf(bhi(q.z), w, acc[5]);
    acc[6] = fmaf(blo(q.w), w, acc[6]);
    acc[7] = fmaf(bhi(q.w), w, acc[7]);
  }
  // gather-reduce over the node's 3 groups (base lane = 15*i + c4)
  const int base = 15 * i + c4;
  float tot[8];
#pragma unroll
  for (int k = 0; k < 8; ++k) {
    tot[k] = __shfl(acc[k], base) + __shfl(acc[k], base + 5) + __shfl(acc[k], base + 10);
  }
  if (ok && p == 0 && node < N_NODES) {
    const float dn = dis[node], sn = selfn[node];
    const uint4 q = *(const uint4*)(tb + (size_t)node * 40 + (c4 << 3));
    const float sv[8] = {blo(q.x), bhi(q.x), blo(q.y), bhi(q.y),
                         blo(q.z), bhi(q.z), blo(q.w), bhi(q.w)};
    float v[8];
#pragma unroll
    for (int k = 0; k < 8; ++k) v[k] = fmaf(dn, tot[k], sv[k] * sn);
    float4* op = (float4*)(out + (size_t)node * 40 + (c4 << 3));
    op[0] = make_float4(v[0], v[1], v[2], v[3]);
    op[1] = make_float4(v[4], v[5], v[6], v[7]);
  }
}

__global__ void bnfinal_k(const float* __restrict__ part, const float* __restrict__ g,
                          const float* __restrict__ be, float* __restrict__ scale,
                          float* __restrict__ shift) {
  const int c = threadIdx.x;  // 64 threads
  float s = 0.f, q = 0.f;
  for (int b = 0; b < 64; ++b) { s += part[b * 128 + c]; q += part[b * 128 + 64 + c]; }
  const float inv = 1.0f / (float)N_NODES;
  const float mu = s * inv;
  const float var = q * inv - mu * mu;
  const float sc = g[c] * rsqrtf(var + 1e-5f);
  scale[c] = sc;
  shift[c] = fmaf(-mu, sc, be[c]);
}

// ---------------- launch ----------------

extern "C" void kernel_launch(void* const* d_in, const int* in_sizes, int n_in,
                              void* d_out, int out_size, void* d_ws, size_t ws_size,
                              hipStream_t stream) {
  const float* x   = (const float*)d_in[0];
  const int*   ei  = (const int*)d_in[1];
  const float* W1  = (const float*)d_in[2];
  const float* b1  = (const float*)d_in[3];
  const float* g1  = (const float*)d_in[4];
  const float* be1 = (const float*)d_in[5];
  const float* W2  = (const float*)d_in[6];
  const float* b2  = (const float*)d_in[7];
  const float* g2  = (const float*)d_in[8];
  const float* be2 = (const float*)d_in[9];
  const float* W3  = (const float*)d_in[10];
  const float* b3  = (const float*)d_in[11];
  float* out = (float*)d_out;
  const int* src = ei;
  const int* dst = ei + N_EDGES;

  char* ws = (char*)d_ws;
  size_t o = 0;
  auto alloc = [&](size_t bytes) -> char* {
    char* p = ws + o;
    o += (bytes + 255) & ~(size_t)255;
    return p;
  };
  int*   gCount  = (int*)alloc((size_t)NBKT * 4);
  int*   gBase   = (int*)alloc(((size_t)NBKT + 1) * 4);
  int*   gCursor = (int*)alloc((size_t)NBKT * 4);
  int*   offsets = (int*)alloc(((size_t)N_NODES + 1) * 4);
  int*   csr_src = (int*)alloc((size_t)N_EDGES * 4);
  float* dis     = (float*)alloc((size_t)N_NODES * 4);
  float* selfn   = (float*)alloc((size_t)N_NODES * 4);
  float* part1   = (float*)alloc(64 * 128 * 4);  // 32 KiB
  float* part2   = (float*)alloc(64 * 128 * 4);  // contiguous with part1
  float* scale1  = (float*)alloc(64 * 4);
  float* shift1  = (float*)alloc(64 * 4);
  float* scale2  = (float*)alloc(64 * 4);
  float* shift2  = (float*)alloc(64 * 4);
  char*  treg    = alloc((size_t)N_NODES * 64 * 4);  // 25.6 MB region
  u16*   hbuf    = (u16*)alloc((size_t)N_NODES * 64 * 2);  // bf16 handoff
  // Region layout: bf16 table tb = [0, 12.8M); csr2 = [12.8M, 25.6M).
  // ebuf (12.8 MB) aliases the tb half and is dead before gemm1 writes it;
  // csr2 persists across all layers. Same-stream ordering makes this safe.
  u16*  tbuf = (u16*)treg;
  uint2* ebuf = (uint2*)treg;
  int2* csr2 = (int2*)(treg + (size_t)N_NODES * 64 * 2);

  hipMemsetAsync(gCount, 0, (size_t)NBKT * 4, stream);
  hipMemsetAsync(part1, 0, 2 * 64 * 128 * 4, stream);  // part1+part2

  bucket_count_k<<<NBLK_E, 256, 0, stream>>>(dst, gCount);
  bucket_scan_k<<<1, 256, 0, stream>>>(gCount, gBase, gCursor, offsets);
  bucket_scatter_k<<<NBLK_E, 256, 0, stream>>>(src, dst, gCursor, ebuf);
  csr_build_k<<<NBKT, 256, 0, stream>>>(ebuf, gBase, offsets, csr_src, dis, selfn);
  pack_k<<<(N_EDGES + 255) / 256, 256, 0, stream>>>(csr_src, dis, csr2);

  const int nagg = (N_NODES + 15) / 16;  // 4 nodes per wave, 4 waves per block

  // layer 1: K=128 -> C=64, fp32 input, no BN
  gemm_k<128, 64, 2, false, false><<<(N_NODES + 31) / 32, 256, 0, stream>>>(
      x, W1, b1, nullptr, nullptr, tbuf);
  agg64_v4_k<true><<<nagg, 256, 0, stream>>>(
      tbuf, csr2, offsets, dis, selfn, hbuf, part1);
  bnfinal_k<<<1, 64, 0, stream>>>(part1, g1, be1, scale1, shift1);

  // layer 2: K=64 -> C=64, bf16 input, BN+ReLU fused into staging
  gemm_k<64, 64, 4, true, true><<<(N_NODES + 63) / 64, 256, 0, stream>>>(
      hbuf, W2, b2, scale1, shift1, tbuf);
  agg64_v4_k<true><<<nagg, 256, 0, stream>>>(
      tbuf, csr2, offsets, dis, selfn, hbuf, part2);
  bnfinal_k<<<1, 64, 0, stream>>>(part2, g2, be2, scale2, shift2);

  // layer 3: K=64 -> C=40, bf16 input, BN+ReLU fused; aggregate to d_out
  gemm_k<64, 40, 4, true, true><<<(N_NODES + 99) / 100, 256, 0, stream>>>(
      hbuf, W3, b3, scale2, shift2, tbuf);
  agg40_v4_k<<<nagg, 256, 0, stream>>>(
      tbuf, csr2, offsets, dis, selfn, out);
}

// Round 10
// 454.419 us; speedup vs baseline: 1.1877x; 1.1877x over previous
//
#include <hip/hip_runtime.h>

#define N_NODES 100000
#define N_EDGES 1600000
#define NBKT 391            // bucket = dst >> 8, 256 nodes per bucket
#define EPB 4096            // edges per block in bucket passes
#define NBLK_E ((N_EDGES + EPB - 1) / EPB)  // 391

typedef unsigned short u16;
typedef unsigned int u32;
typedef short bf16x8 __attribute__((ext_vector_type(8)));  // MFMA A/B frag (8 bf16)
typedef float f32x4 __attribute__((ext_vector_type(4)));   // MFMA C/D frag
struct alignas(8) bf4 { u16 a, b, c, d; };

__device__ __forceinline__ float blo(u32 u) { return __uint_as_float(u << 16); }
__device__ __forceinline__ float bhi(u32 u) { return __uint_as_float(u & 0xffff0000u); }
__device__ __forceinline__ u16 f2bf(float f) {  // RTNE
  u32 u = __float_as_uint(f);
  return (u16)((u + 0x7fffu + ((u >> 16) & 1u)) >> 16);
}
__device__ __forceinline__ u32 pack2(float a, float b) {
  return (u32)f2bf(a) | ((u32)f2bf(b) << 16);
}

// ---------------- CSR build: two-level bucket counting sort ----------------

__global__ __launch_bounds__(256) void bucket_count_k(const int* __restrict__ dst,
                                                      int* __restrict__ gCount) {
  __shared__ int h[NBKT];
  for (int i = threadIdx.x; i < NBKT; i += 256) h[i] = 0;
  __syncthreads();
  const int e0 = blockIdx.x * EPB;
  const int eN = min(EPB, N_EDGES - e0);
  for (int i = threadIdx.x; i < eN; i += 256) atomicAdd(&h[dst[e0 + i] >> 8], 1);
  __syncthreads();
  for (int i = threadIdx.x; i < NBKT; i += 256)
    if (h[i]) atomicAdd(&gCount[i], h[i]);
}

__global__ void bucket_scan_k(const int* __restrict__ gCount,
                              int* __restrict__ gBase,
                              int* __restrict__ gCursor,
                              int* __restrict__ offsets) {
  __shared__ int sm[512];
  const int t = threadIdx.x;  // 256
  const int c0 = (t < NBKT) ? gCount[t] : 0;
  const int c1 = (t + 256 < NBKT) ? gCount[t + 256] : 0;
  sm[t] = c0; sm[t + 256] = c1;
  __syncthreads();
  for (int off = 1; off < 512; off <<= 1) {
    const int v0 = (t >= off) ? sm[t - off] : 0;
    const int v1 = (t + 256 >= off) ? sm[t + 256 - off] : 0;
    __syncthreads();
    sm[t] += v0; sm[t + 256] += v1;
    __syncthreads();
  }
  if (t < NBKT)       { const int b = sm[t] - c0;       gBase[t] = b;       gCursor[t] = b; }
  if (t + 256 < NBKT) { const int b = sm[t + 256] - c1; gBase[t + 256] = b; gCursor[t + 256] = b; }
  if (t == 0) { gBase[NBKT] = N_EDGES; offsets[N_NODES] = N_EDGES; }
}

// chunk -> LDS counting-sort by bucket -> coalesced run writes into ebuf
__global__ __launch_bounds__(256) void bucket_scatter_k(const int* __restrict__ src,
                                                        const int* __restrict__ dst,
                                                        int* __restrict__ gCursor,
                                                        uint2* __restrict__ ebuf) {
  __shared__ int cnt[NBKT];
  __shared__ int inc[512];
  __shared__ int gb[NBKT];
  __shared__ int cur[NBKT];
  __shared__ uint2 st[EPB];
  const int t = threadIdx.x;
  for (int i = t; i < NBKT; i += 256) cnt[i] = 0;
  __syncthreads();
  const int e0 = blockIdx.x * EPB;
  const int eN = min(EPB, N_EDGES - e0);
  for (int i = t; i < eN; i += 256) atomicAdd(&cnt[dst[e0 + i] >> 8], 1);
  __syncthreads();
  const int c0 = (t < NBKT) ? cnt[t] : 0;
  const int c1 = (t + 256 < NBKT) ? cnt[t + 256] : 0;
  inc[t] = c0; inc[t + 256] = c1;
  __syncthreads();
  for (int off = 1; off < 512; off <<= 1) {
    const int v0 = (t >= off) ? inc[t - off] : 0;
    const int v1 = (t + 256 >= off) ? inc[t + 256 - off] : 0;
    __syncthreads();
    inc[t] += v0; inc[t + 256] += v1;
    __syncthreads();
  }
  if (t < NBKT) {
    if (c0) gb[t] = atomicAdd(&gCursor[t], c0);
    cur[t] = inc[t] - c0;
  }
  if (t + 256 < NBKT) {
    if (c1) gb[t + 256] = atomicAdd(&gCursor[t + 256], c1);
    cur[t + 256] = inc[t + 256] - c1;
  }
  __syncthreads();
  for (int i = t; i < eN; i += 256) {
    const int d = dst[e0 + i];
    const int b = d >> 8;
    const int p = atomicAdd(&cur[b], 1);
    st[p] = make_uint2((unsigned)src[e0 + i], (unsigned)d);
  }
  __syncthreads();
  for (int i = t; i < eN; i += 256) {
    const uint2 e = st[i];
    const int b = (int)(e.y >> 8);
    const int excl = inc[b] - cnt[b];
    ebuf[gb[b] + (i - excl)] = e;   // adjacent i in a run -> adjacent addrs
  }
}

// one block per bucket: per-node count/scan/scatter in LDS; emits offsets,
// dis/selfn, and csr_src (src in low 20 bits).
__global__ __launch_bounds__(256) void csr_build_k(const uint2* __restrict__ ebuf,
                                                   const int* __restrict__ gBase,
                                                   int* __restrict__ offsets,
                                                   int* __restrict__ csr_src,
                                                   float* __restrict__ dis,
                                                   float* __restrict__ selfn) {
  __shared__ int cnt[256];
  __shared__ int inc[256];
  __shared__ int cur[256];
  const int t = threadIdx.x;
  const int b = blockIdx.x;
  const int ebeg = gBase[b], eend = gBase[b + 1];
  cnt[t] = 0;
  __syncthreads();
  for (int e = ebeg + t; e < eend; e += 256) atomicAdd(&cnt[ebuf[e].y & 255], 1);
  __syncthreads();
  const int c = cnt[t];
  inc[t] = c;
  __syncthreads();
  for (int off = 1; off < 256; off <<= 1) {
    const int v = (t >= off) ? inc[t - off] : 0;
    __syncthreads();
    inc[t] += v;
    __syncthreads();
  }
  const int node = (b << 8) + t;
  const int goff = ebeg + inc[t] - c;
  cur[t] = goff;
  if (node < N_NODES) {
    offsets[node] = goff;
    const float deg = (float)c + 1.0f;  // +1 self loop
    dis[node] = rsqrtf(deg);
    selfn[node] = 1.0f / deg;
  }
  __syncthreads();
  for (int e = ebeg + t; e < eend; e += 256) {
    const uint2 ed = ebuf[e];
    const int p = atomicAdd(&cur[ed.y & 255], 1);
    csr_src[p] = (int)ed.x;
  }
}

// fold edge weight: csr2[i] = (src, dis[src]) — one random 4B gather per edge
// ONCE instead of per-layer.
__global__ __launch_bounds__(256) void pack_k(const int* __restrict__ csr_src,
                                              const float* __restrict__ dis,
                                              int2* __restrict__ csr2) {
  const int i = blockIdx.x * 256 + threadIdx.x;
  if (i < N_EDGES) {
    const int v = csr_src[i] & 0xFFFFF;
    csr2[i] = make_int2(v, __float_as_int(dis[v]));
  }
}

// ---------------- GEMM (MFMA bf16): out[N,C] = act(A)[N,K] @ W[K,C] + bias ----
// Block = 64 rows, 4 waves; wave w computes rows w*16..w*16+15 x CPAD cols via
// 16x16x32 bf16 MFMA. A staged to LDS as bf16 (BN+ReLU fused, fp32 math);
// W^T staged to LDS as bf16 (B-frag needs k-contiguous per col). LDS stride
// K+8 u16 => row stride 272/144 B => bank step 4 => 2-way (free) ds_read_b128.
// A-frag: A[m=lane&15][k=quad*8+j]; B-frag: W[k=quad*8+j][col=lane&15];
// D: col=lane&15, row=quad*4+reg.

template <int K, int C, bool BN, bool BF16IN>
__global__ __launch_bounds__(256) void gemm_mfma_k(const void* __restrict__ Av,
                                                   const float* __restrict__ W,
                                                   const float* __restrict__ bias,
                                                   const float* __restrict__ scale,
                                                   const float* __restrict__ shift,
                                                   u16* __restrict__ out) {
  constexpr int CPAD = (C + 15) & ~15;   // 64 or 48
  constexpr int CT = CPAD / 16;          // col tiles
  constexpr int KS = K + 8;              // padded LDS row stride (u16)
  __shared__ u16 Al[64 * KS];
  __shared__ u16 Wt[CPAD * KS];
  const int tid = threadIdx.x;
  const int row0 = blockIdx.x * 64;
  // stage W^T (bf16); cols C..CPAD-1 left unwritten (their D cols never stored)
  for (int i = tid; i < K * C; i += 256) {
    const int k = i / C, c = i - k * C;
    Wt[c * KS + k] = f2bf(W[i]);
  }
  // stage A (bf16), 4 elements per step, coalesced; BN+ReLU in fp32
  for (int i = tid; i < 64 * K / 4; i += 256) {
    const int e0 = i * 4;
    const int r = e0 / K, k = e0 - (e0 / K) * K;
    const int gr = row0 + r;
    float v0 = 0.f, v1 = 0.f, v2 = 0.f, v3 = 0.f;
    if (gr < N_NODES) {
      if (BF16IN) {
        const uint2 u = *(const uint2*)((const u16*)Av + (size_t)gr * K + k);
        v0 = blo(u.x); v1 = bhi(u.x); v2 = blo(u.y); v3 = bhi(u.y);
      } else {
        const float4 a = *(const float4*)((const float*)Av + (size_t)gr * K + k);
        v0 = a.x; v1 = a.y; v2 = a.z; v3 = a.w;
      }
      if (BN) {
        const float4 sc = *(const float4*)(scale + k);
        const float4 sh = *(const float4*)(shift + k);
        v0 = fmaxf(fmaf(v0, sc.x, sh.x), 0.f);
        v1 = fmaxf(fmaf(v1, sc.y, sh.y), 0.f);
        v2 = fmaxf(fmaf(v2, sc.z, sh.z), 0.f);
        v3 = fmaxf(fmaf(v3, sc.w, sh.w), 0.f);
      }
    }
    ushort4 pk;
    pk.x = f2bf(v0); pk.y = f2bf(v1); pk.z = f2bf(v2); pk.w = f2bf(v3);
    *(ushort4*)(Al + r * KS + k) = pk;
  }
  __syncthreads();
  const int wv = tid >> 6;
  const int lane = tid & 63;
  const int mr = lane & 15;     // A row / B col / D col within tile
  const int kq = lane >> 4;     // k quad
  f32x4 acc[CT];
#pragma unroll
  for (int t = 0; t < CT; ++t) acc[t] = (f32x4){0.f, 0.f, 0.f, 0.f};
  const u16* ab = Al + (wv * 16 + mr) * KS + kq * 8;
#pragma unroll
  for (int ks = 0; ks < K; ks += 32) {
    const bf16x8 af = *(const bf16x8*)(ab + ks);
#pragma unroll
    for (int t = 0; t < CT; ++t) {
      const bf16x8 bf = *(const bf16x8*)(Wt + (t * 16 + mr) * KS + kq * 8 + ks);
      acc[t] = __builtin_amdgcn_mfma_f32_16x16x32_bf16(af, bf, acc[t], 0, 0, 0);
    }
  }
#pragma unroll
  for (int t = 0; t < CT; ++t) {
    const int col = t * 16 + mr;
    if (col < C) {
      const float bb = bias[col];
#pragma unroll
      for (int r = 0; r < 4; ++r) {
        const int gr = row0 + wv * 16 + kq * 4 + r;
        if (gr < N_NODES) out[(size_t)gr * C + col] = f2bf(acc[t][r] + bb);
      }
    }
  }
}

// ---------------- aggregation: 4 nodes per wave, register accumulate ---------
// (R7 config: plain loads — nontemporal was measured neutral-to-negative.)
// Wave = 8 groups x 8 lanes, 2 groups per node; one uint4 instr gathers 8 rows
// (1 KB); unroll 4 => ~4 KB in flight across 4 independent node chains.
// bf16 out for the next layer's MFMA GEMM; BN stats in fp32.

template <bool STATS>
__global__ __launch_bounds__(256) void agg64_k(const u16* __restrict__ tb,
                                               const int2* __restrict__ csr2,
                                               const int* __restrict__ offs,
                                               const float* __restrict__ dis,
                                               const float* __restrict__ selfn,
                                               u16* __restrict__ out,
                                               float* __restrict__ part) {
  __shared__ float s_sum[64];
  __shared__ float s_sq[64];
  if (STATS) {
    if (threadIdx.x < 64) { s_sum[threadIdx.x] = 0.f; s_sq[threadIdx.x] = 0.f; }
    __syncthreads();
  }
  const int lane = threadIdx.x & 63;
  const int nb = (blockIdx.x * 4 + (threadIdx.x >> 6)) * 4;
  const int g = lane >> 3;
  const int c4 = lane & 7;
  const int i = g >> 1;
  const int p = g & 1;
  const int node = nb + i;
  int beg = 0, end = 0;
  if (node < N_NODES) { beg = offs[node]; end = offs[node + 1]; }
  int iters = (end - beg + 1) >> 1;            // ceil(deg/2)
  iters = max(iters, __shfl_xor(iters, 8));    // wave-max across groups
  iters = max(iters, __shfl_xor(iters, 16));
  iters = max(iters, __shfl_xor(iters, 32));
  float acc[8];
#pragma unroll
  for (int k = 0; k < 8; ++k) acc[k] = 0.f;
  const u16* __restrict__ tc = tb + (c4 << 3);
  int e = beg + p;
#pragma unroll 4
  for (int it = 0; it < iters; ++it) {
    int2 ev = make_int2(0, 0);
    if (e < end) ev = csr2[e];
    e += 2;
    const int s = ev.x & 0xFFFFF;
    const float w = __int_as_float(ev.y);      // 0 when inactive
    const uint4 q = *(const uint4*)(tc + (size_t)s * 64);
    acc[0] = fmaf(blo(q.x), w, acc[0]);
    acc[1] = fmaf(bhi(q.x), w, acc[1]);
    acc[2] = fmaf(blo(q.y), w, acc[2]);
    acc[3] = fmaf(bhi(q.y), w, acc[3]);
    acc[4] = fmaf(blo(q.z), w, acc[4]);
    acc[5] = fmaf(bhi(q.z), w, acc[5]);
    acc[6] = fmaf(blo(q.w), w, acc[6]);
    acc[7] = fmaf(bhi(q.w), w, acc[7]);
  }
  // combine the node's two groups (single butterfly step)
#pragma unroll
  for (int k = 0; k < 8; ++k) acc[k] += __shfl_xor(acc[k], 8);
  float v[8];
  const bool writer = (p == 0) && (node < N_NODES);
  if (writer) {
    const float dn = dis[node], sn = selfn[node];
    const uint4 q = *(const uint4*)(tb + (size_t)node * 64 + (c4 << 3));
    const float sv[8] = {blo(q.x), bhi(q.x), blo(q.y), bhi(q.y),
                         blo(q.z), bhi(q.z), blo(q.w), bhi(q.w)};
#pragma unroll
    for (int k = 0; k < 8; ++k) v[k] = fmaf(dn, acc[k], sv[k] * sn);
    uint4 o;
    o.x = pack2(v[0], v[1]); o.y = pack2(v[2], v[3]);
    o.z = pack2(v[4], v[5]); o.w = pack2(v[6], v[7]);
    *(uint4*)(out + (size_t)node * 64 + (c4 << 3)) = o;
  }
  if (STATS) {
    if (writer) {
#pragma unroll
      for (int k = 0; k < 8; ++k) {
        atomicAdd(&s_sum[(c4 << 3) + k], v[k]);
        atomicAdd(&s_sq[(c4 << 3) + k], v[k] * v[k]);
      }
    }
    __syncthreads();
    if (threadIdx.x < 128) {
      const int c = threadIdx.x & 63;
      const float val = (threadIdx.x < 64) ? s_sum[c] : s_sq[c];
      atomicAdd(&part[(blockIdx.x & 63) * 128 + (threadIdx.x < 64 ? c : 64 + c)], val);
    }
  }
}

// C=40 variant: 12 groups of 5 lanes (lanes 60..63 idle); 3 groups per node;
// lane loads 8 bf16 (row = 80 B = 5 x 16 B, aligned). fp32 out.
__global__ __launch_bounds__(256) void agg40_k(const u16* __restrict__ tb,
                                               const int2* __restrict__ csr2,
                                               const int* __restrict__ offs,
                                               const float* __restrict__ dis,
                                               const float* __restrict__ selfn,
                                               float* __restrict__ out) {
  const int lane = threadIdx.x & 63;
  const int nb = (blockIdx.x * 4 + (threadIdx.x >> 6)) * 4;
  const bool ok = lane < 60;
  const int g = ok ? (lane / 5) : 0;
  const int c4 = ok ? (lane - g * 5) : 0;
  const int i = g / 3;
  const int p = g - i * 3;
  const int node = nb + i;
  int beg = 0, end = 0;
  if (ok && node < N_NODES) { beg = offs[node]; end = offs[node + 1]; }
  int iters = (end - beg + 2) / 3;             // ceil(deg/3)
  iters = max(iters, __shfl_xor(iters, 1));
  iters = max(iters, __shfl_xor(iters, 2));
  iters = max(iters, __shfl_xor(iters, 4));
  iters = max(iters, __shfl_xor(iters, 8));
  iters = max(iters, __shfl_xor(iters, 16));
  iters = max(iters, __shfl_xor(iters, 32));
  float acc[8];
#pragma unroll
  for (int k = 0; k < 8; ++k) acc[k] = 0.f;
  const u16* __restrict__ tc = tb + (c4 << 3);
  int e = beg + p;
#pragma unroll 4
  for (int it = 0; it < iters; ++it) {
    int2 ev = make_int2(0, 0);
    if (e < end) ev = csr2[e];
    e += 3;
    const int s = ev.x & 0xFFFFF;
    const float w = __int_as_float(ev.y);
    const uint4 q = *(const uint4*)(tc + (size_t)s * 40);
    acc[0] = fmaf(blo(q.x), w, acc[0]);
    acc[1] = fmaf(bhi(q.x), w, acc[1]);
    acc[2] = fmaf(blo(q.y), w, acc[2]);
    acc[3] = fmaf(bhi(q.y), w, acc[3]);
    acc[4] = fmaf(blo(q.z), w, acc[4]);
    acc[5] = fmaf(bhi(q.z), w, acc[5]);
    acc[6] = fmaf(blo(q.w), w, acc[6]);
    acc[7] = fmaf(bhi(q.w), w, acc[7]);
  }
  // gather-reduce over the node's 3 groups (base lane = 15*i + c4)
  const int base = 15 * i + c4;
  float tot[8];
#pragma unroll
  for (int k = 0; k < 8; ++k) {
    tot[k] = __shfl(acc[k], base) + __shfl(acc[k], base + 5) + __shfl(acc[k], base + 10);
  }
  if (ok && p == 0 && node < N_NODES) {
    const float dn = dis[node], sn = selfn[node];
    const uint4 q = *(const uint4*)(tb + (size_t)node * 40 + (c4 << 3));
    const float sv[8] = {blo(q.x), bhi(q.x), blo(q.y), bhi(q.y),
                         blo(q.z), bhi(q.z), blo(q.w), bhi(q.w)};
    float v[8];
#pragma unroll
    for (int k = 0; k < 8; ++k) v[k] = fmaf(dn, tot[k], sv[k] * sn);
    float4* op = (float4*)(out + (size_t)node * 40 + (c4 << 3));
    op[0] = make_float4(v[0], v[1], v[2], v[3]);
    op[1] = make_float4(v[4], v[5], v[6], v[7]);
  }
}

// parallel BN finalize: 256 threads, 4 partial sets of 16 bucket-rows each
__global__ void bnfinal_k(const float* __restrict__ part, const float* __restrict__ g,
                          const float* __restrict__ be, float* __restrict__ scale,
                          float* __restrict__ shift) {
  __shared__ float ss[256], qq[256];
  const int c = threadIdx.x & 63;
  const int qa = threadIdx.x >> 6;
  float s = 0.f, q = 0.f;
  for (int b = qa * 16; b < qa * 16 + 16; ++b) {
    s += part[b * 128 + c];
    q += part[b * 128 + 64 + c];
  }
  ss[threadIdx.x] = s; qq[threadIdx.x] = q;
  __syncthreads();
  if (threadIdx.x < 64) {
    s = ss[c] + ss[c + 64] + ss[c + 128] + ss[c + 192];
    q = qq[c] + qq[c + 64] + qq[c + 128] + qq[c + 192];
    const float inv = 1.0f / (float)N_NODES;
    const float mu = s * inv;
    const float var = q * inv - mu * mu;
    const float sc = g[c] * rsqrtf(var + 1e-5f);
    scale[c] = sc;
    shift[c] = fmaf(-mu, sc, be[c]);
  }
}

// ---------------- launch ----------------

extern "C" void kernel_launch(void* const* d_in, const int* in_sizes, int n_in,
                              void* d_out, int out_size, void* d_ws, size_t ws_size,
                              hipStream_t stream) {
  const float* x   = (const float*)d_in[0];
  const int*   ei  = (const int*)d_in[1];
  const float* W1  = (const float*)d_in[2];
  const float* b1  = (const float*)d_in[3];
  const float* g1  = (const float*)d_in[4];
  const float* be1 = (const float*)d_in[5];
  const float* W2  = (const float*)d_in[6];
  const float* b2  = (const float*)d_in[7];
  const float* g2  = (const float*)d_in[8];
  const float* be2 = (const float*)d_in[9];
  const float* W3  = (const float*)d_in[10];
  const float* b3  = (const float*)d_in[11];
  float* out = (float*)d_out;
  const int* src = ei;
  const int* dst = ei + N_EDGES;

  char* ws = (char*)d_ws;
  size_t o = 0;
  auto alloc = [&](size_t bytes) -> char* {
    char* p = ws + o;
    o += (bytes + 255) & ~(size_t)255;
    return p;
  };
  int*   gCount  = (int*)alloc((size_t)NBKT * 4);
  int*   gBase   = (int*)alloc(((size_t)NBKT + 1) * 4);
  int*   gCursor = (int*)alloc((size_t)NBKT * 4);
  int*   offsets = (int*)alloc(((size_t)N_NODES + 1) * 4);
  int*   csr_src = (int*)alloc((size_t)N_EDGES * 4);
  float* dis     = (float*)alloc((size_t)N_NODES * 4);
  float* selfn   = (float*)alloc((size_t)N_NODES * 4);
  float* part1   = (float*)alloc(64 * 128 * 4);  // 32 KiB
  float* part2   = (float*)alloc(64 * 128 * 4);  // contiguous with part1
  float* scale1  = (float*)alloc(64 * 4);
  float* shift1  = (float*)alloc(64 * 4);
  float* scale2  = (float*)alloc(64 * 4);
  float* shift2  = (float*)alloc(64 * 4);
  char*  treg    = alloc((size_t)N_NODES * 64 * 4);  // 25.6 MB region
  u16*   hbuf    = (u16*)alloc((size_t)N_NODES * 64 * 2);  // bf16 handoff
  // Region layout: bf16 table tb = [0, 12.8M); csr2 = [12.8M, 25.6M).
  // ebuf (12.8 MB) aliases the tb half and is dead before gemm1 writes it;
  // csr2 persists across all layers. Same-stream ordering makes this safe.
  u16*  tbuf = (u16*)treg;
  uint2* ebuf = (uint2*)treg;
  int2* csr2 = (int2*)(treg + (size_t)N_NODES * 64 * 2);

  hipMemsetAsync(gCount, 0, (size_t)NBKT * 4, stream);
  hipMemsetAsync(part1, 0, 2 * 64 * 128 * 4, stream);  // part1+part2

  bucket_count_k<<<NBLK_E, 256, 0, stream>>>(dst, gCount);
  bucket_scan_k<<<1, 256, 0, stream>>>(gCount, gBase, gCursor, offsets);
  bucket_scatter_k<<<NBLK_E, 256, 0, stream>>>(src, dst, gCursor, ebuf);
  csr_build_k<<<NBKT, 256, 0, stream>>>(ebuf, gBase, offsets, csr_src, dis, selfn);
  pack_k<<<(N_EDGES + 255) / 256, 256, 0, stream>>>(csr_src, dis, csr2);

  const int nagg = (N_NODES + 15) / 16;   // 4 nodes per wave, 4 waves per block
  const int ngemm = (N_NODES + 63) / 64;  // 64 rows per block

  // layer 1: K=128 -> C=64, fp32 input, no BN
  gemm_mfma_k<128, 64, false, false><<<ngemm, 256, 0, stream>>>(
      x, W1, b1, nullptr, nullptr, tbuf);
  agg64_k<true><<<nagg, 256, 0, stream>>>(
      tbuf, csr2, offsets, dis, selfn, hbuf, part1);
  bnfinal_k<<<1, 256, 0, stream>>>(part1, g1, be1, scale1, shift1);

  // layer 2: K=64 -> C=64, bf16 input, BN+ReLU fused into staging
  gemm_mfma_k<64, 64, true, true><<<ngemm, 256, 0, stream>>>(
      hbuf, W2, b2, scale1, shift1, tbuf);
  agg64_k<true><<<nagg, 256, 0, stream>>>(
      tbuf, csr2, offsets, dis, selfn, hbuf, part2);
  bnfinal_k<<<1, 256, 0, stream>>>(part2, g2, be2, scale2, shift2);

  // layer 3: K=64 -> C=40, bf16 input, BN+ReLU fused; aggregate to d_out
  gemm_mfma_k<64, 40, true, true><<<ngemm, 256, 0, stream>>>(
      hbuf, W3, b3, scale2, shift2, tbuf);
  agg40_k<<<nagg, 256, 0, stream>>>(
      tbuf, csr2, offsets, dis, selfn, out);
}